// Round 3
// baseline (225.354 us; speedup 1.0000x reference)
//
#include <hip/hip_runtime.h>

// MultiHeadAttention_137438953529 on gfx950.
// B=8, S=1024, E=1024, H=16, D=64.  The reference's reshapes are flat
// reinterpretations => attention mixes only groups of 8 consecutive rows of
// the (8192 x 1024) projected matrices, per 64-wide head slice.
//
// R3: GEMM redesigned around L3-traffic + TLP:
//  - A (f32 X) read per-wave direct from global (L1/L2-hot), converted with
//    v_cvt_pk_bf16_f32; no A-LDS at all.
//  - B (bf16 W) double-buffered 8 KiB LDS via global_load_lds, source-side
//    chunk swizzle (c ^= (row>>1)&3) -> conflict-free ds_read_b128.
//  - XCD-family 1D block swizzle: each XCD owns whole row-blocks with all 8
//    col-blocks consecutive -> A-slice + W panel L2-resident, X through L3 ~1x.
//  - 16 KiB LDS, ~150 VGPR -> ~3 blocks/CU; plain __syncthreads (TLP hides).

typedef __attribute__((ext_vector_type(4))) float f32x4;
typedef __attribute__((ext_vector_type(8))) short bf16x8;   // MFMA A/B fragment
typedef __attribute__((ext_vector_type(8))) unsigned short u16x8;

__device__ __forceinline__ unsigned short f2bf(float f) {
  unsigned int u = __builtin_bit_cast(unsigned int, f);
  u += 0x7fffu + ((u >> 16) & 1u);          // round-to-nearest-even
  return (unsigned short)(u >> 16);
}
__device__ __forceinline__ float bf2f(unsigned short b) {
  return __builtin_bit_cast(float, ((unsigned int)b) << 16);
}
__device__ __forceinline__ u16x8 pack8(f32x4 a, f32x4 b) {
  u16x8 o;
  o[0] = f2bf(a[0]); o[1] = f2bf(a[1]); o[2] = f2bf(a[2]); o[3] = f2bf(a[3]);
  o[4] = f2bf(b[0]); o[5] = f2bf(b[1]); o[6] = f2bf(b[2]); o[7] = f2bf(b[3]);
  return o;
}
// 8x f32 -> bf16x8 via packed cvt (1 inst / 2 elems)
__device__ __forceinline__ bf16x8 cvt8(f32x4 a, f32x4 b) {
  union { unsigned int u[4]; bf16x8 v; } r;
  asm("v_cvt_pk_bf16_f32 %0, %1, %2" : "=v"(r.u[0]) : "v"(a[0]), "v"(a[1]));
  asm("v_cvt_pk_bf16_f32 %0, %1, %2" : "=v"(r.u[1]) : "v"(a[2]), "v"(a[3]));
  asm("v_cvt_pk_bf16_f32 %0, %1, %2" : "=v"(r.u[2]) : "v"(b[0]), "v"(b[1]));
  asm("v_cvt_pk_bf16_f32 %0, %1, %2" : "=v"(r.u[3]) : "v"(b[2]), "v"(b[3]));
  return r.v;
}

__device__ __forceinline__ void gload_lds16(const unsigned short* g, unsigned short* l) {
  __builtin_amdgcn_global_load_lds(
      (const __attribute__((address_space(1))) unsigned int*)g,
      (__attribute__((address_space(3))) unsigned int*)l, 16, 0, 0);
}

// --------------------------------------------------- W -> bf16 (linear layout)
__global__ __launch_bounds__(256) void cvt_w(const float* __restrict__ Wq,
                                             const float* __restrict__ Wk,
                                             const float* __restrict__ Wv,
                                             unsigned short* __restrict__ Wb) {
  int i = blockIdx.x * 256 + threadIdx.x;     // 0 .. 393216 (3 * 131072 chunks of 8)
  int proj = i >> 17;
  int local = i & 131071;
  const float* src = (proj == 0 ? Wq : proj == 1 ? Wk : Wv) + (size_t)local * 8;
  f32x4 a = reinterpret_cast<const f32x4*>(src)[0];
  f32x4 b = reinterpret_cast<const f32x4*>(src)[1];
  *reinterpret_cast<u16x8*>(Wb + (size_t)proj * 1048576 + (size_t)local * 8) = pack8(a, b);
}

// ------------------------------------------------------------ QKV projection
// C[8192x1024] = X @ W^T + bias per proj.  BM=BN=128, BK=32, 256 threads,
// 4 waves (2x2), per-wave 64x64 (4x4 frags of 16x16x32 bf16 MFMA), 32 K-iters.
__global__ __launch_bounds__(256) void gemm3(
    const float* __restrict__ Xq, const float* __restrict__ Xk, const float* __restrict__ Xv,
    const unsigned short* __restrict__ Wb,
    const float* __restrict__ bq, const float* __restrict__ bk, const float* __restrict__ bv,
    unsigned short* __restrict__ QKV) {
  // XCD-family decode: d = ((proj*8 + xg)*8 + y)*8 + xcd.  XCD c (dispatch
  // round-robin d%8) owns x in [8c, 8c+8); the 8 col-blocks (y) of one x are
  // consecutive on that XCD -> A-slice (512 KB) + W panel (2 MB) L2-resident.
  const int d = blockIdx.x;
  const int xcd = d & 7;
  const int k5 = d >> 3;
  const int y = k5 & 7;
  const int rest = k5 >> 3;       // 0..23
  const int proj = rest >> 3;     // 0..2
  const int xg = rest & 7;
  const int x = xcd * 8 + xg;     // 0..63

  const float* X = (proj == 0) ? Xq : (proj == 1) ? Xk : Xv;
  const float* bias = (proj == 0) ? bq : (proj == 1) ? bk : bv;
  const unsigned short* W = Wb + (size_t)proj * 1048576;
  unsigned short* O = QKV + (size_t)proj * 8388608;

  const int rowBase = x * 128;
  const int colBase = y * 128;

  __shared__ alignas(16) unsigned short Bs[2][4096];   // 2 x [128 rows][32 k] bf16

  const int t = threadIdx.x;
  const int l = t & 63;
  const int w = t >> 6;
  const int wr = w >> 1, wc = w & 1;

  f32x4 acc[4][4];
#pragma unroll
  for (int m = 0; m < 4; ++m)
#pragma unroll
    for (int n = 0; n < 4; ++n) acc[m][n] = f32x4{0.f, 0.f, 0.f, 0.f};

  // A: per-lane global f32 pointers (row = wave's 64-row panel, 8-k slice)
  const float* aP[4];
#pragma unroll
  for (int m = 0; m < 4; ++m)
    aP[m] = X + (size_t)(rowBase + wr * 64 + m * 16 + (l & 15)) * 1024 + (l >> 4) * 8;

  // B read offsets (ushort units), source-swizzle-matched: physical chunk
  // g^s holds source chunk g, s = (row>>1)&3
  int boff[4];
#pragma unroll
  for (int n = 0; n < 4; ++n) {
    const int row = wc * 64 + n * 16 + (l & 15);
    const int g = l >> 4;
    boff[n] = row * 32 + ((g ^ ((row >> 1) & 3)) * 8);
  }

  // B staging: thread t, call j: dest byte o = (j*4+w)*1024 + l*16 (linear
  // wave-uniform + lane*16); row = o>>6, phys chunk c = l&3; source chunk
  // c' = c ^ ((row>>1)&3)
  const int srow0 = w * 16 + (l >> 2);
  const int sc = l & 3;
#define STAGE_B(buf, kt)                                                          \
  {                                                                               \
    _Pragma("unroll") for (int j = 0; j < 2; ++j) {                               \
      const int row = j * 64 + srow0;                                             \
      const int cp = sc ^ ((row >> 1) & 3);                                       \
      gload_lds16(W + (size_t)(colBase + row) * 1024 + (kt) * 32 + cp * 8,        \
                  &Bs[buf][0] + (j * 4 + w) * 512 + l * 8);                       \
    }                                                                             \
  }

  STAGE_B(0, 0);
  __syncthreads();

  for (int kt = 0; kt < 32; ++kt) {
    // issue A f32 loads (L1/L2-hot; latency hidden under stage+ds_reads)
    f32x4 a0[4], a1[4];
#pragma unroll
    for (int m = 0; m < 4; ++m) {
      a0[m] = *reinterpret_cast<const f32x4*>(aP[m] + kt * 32);
      a1[m] = *reinterpret_cast<const f32x4*>(aP[m] + kt * 32 + 4);
    }
    // stage next B tile
    if (kt + 1 < 32) STAGE_B((kt + 1) & 1, kt + 1);
    // B fragments from current tile
    bf16x8 bfr[4];
#pragma unroll
    for (int n = 0; n < 4; ++n)
      bfr[n] = *reinterpret_cast<const bf16x8*>(&Bs[kt & 1][0] + boff[n]);
    // convert A
    bf16x8 af[4];
#pragma unroll
    for (int m = 0; m < 4; ++m) af[m] = cvt8(a0[m], a1[m]);
    // MFMA
#pragma unroll
    for (int m = 0; m < 4; ++m)
#pragma unroll
      for (int n = 0; n < 4; ++n)
        acc[m][n] = __builtin_amdgcn_mfma_f32_16x16x32_bf16(af[m], bfr[n], acc[m][n], 0, 0, 0);
    __syncthreads();   // drains this iter's stage (vmcnt) before buffer reuse
  }

  // epilogue: C/D layout col=lane&15, row=(lane>>4)*4+reg
#pragma unroll
  for (int n = 0; n < 4; ++n) {
    const int col = colBase + wc * 64 + n * 16 + (l & 15);
    const float bn = bias[col];
#pragma unroll
    for (int m = 0; m < 4; ++m) {
      const int row0 = rowBase + wr * 64 + m * 16 + (l >> 4) * 4;
#pragma unroll
      for (int j = 0; j < 4; ++j)
        O[(size_t)(row0 + j) * 1024 + col] = f2bf(acc[m][n][j] + bn);
    }
  }
}

// ------------------------------------------------------------------ attention
// thread = (n group, head h, d-quarter dq, row-half rh): 4 q-rows x 16 d-cols
// of the 8-key attention; QK partial dots reduced across 4 dq lanes.
__global__ __launch_bounds__(256) void attn_kernel(const unsigned short* __restrict__ QKV,
                                                   float* __restrict__ out) {
  const int t = threadIdx.x;
  const int lane = t & 63;
  const int dq = lane & 3;
  const int h = (lane >> 2) & 15;
  const int rh = (t >> 6) & 1;
  const int n = blockIdx.x * 2 + (t >> 7);

  const unsigned short* Q = QKV;
  const unsigned short* K = QKV + (size_t)8388608;
  const unsigned short* V = QKV + (size_t)16777216;
  const size_t gbase = (size_t)n * 8192;
  const int coff = h * 64 + dq * 16;

  float q[4][16];
#pragma unroll
  for (int r = 0; r < 4; ++r) {
    const unsigned short* qp = Q + gbase + (size_t)(rh * 4 + r) * 1024 + coff;
    u16x8 a = *reinterpret_cast<const u16x8*>(qp);
    u16x8 b = *reinterpret_cast<const u16x8*>(qp + 8);
#pragma unroll
    for (int c = 0; c < 8; ++c) { q[r][c] = bf2f(a[c]); q[r][8 + c] = bf2f(b[c]); }
  }

  float s[4][8];
#pragma unroll
  for (int r = 0; r < 4; ++r)
#pragma unroll
    for (int j = 0; j < 8; ++j) s[r][j] = 0.f;

#pragma unroll
  for (int j = 0; j < 8; ++j) {
    const unsigned short* kp = K + gbase + (size_t)j * 1024 + coff;
    u16x8 a = *reinterpret_cast<const u16x8*>(kp);
    u16x8 b = *reinterpret_cast<const u16x8*>(kp + 8);
    float kv[16];
#pragma unroll
    for (int c = 0; c < 8; ++c) { kv[c] = bf2f(a[c]); kv[8 + c] = bf2f(b[c]); }
#pragma unroll
    for (int r = 0; r < 4; ++r) {
      float acc = 0.f;
#pragma unroll
      for (int c = 0; c < 16; ++c) acc += q[r][c] * kv[c];
      s[r][j] += acc;
    }
  }

#pragma unroll
  for (int r = 0; r < 4; ++r)
#pragma unroll
    for (int j = 0; j < 8; ++j) {
      float v = s[r][j];
      v += __shfl_xor(v, 1, 64);
      v += __shfl_xor(v, 2, 64);
      s[r][j] = v;
    }

  float p[4][8];
#pragma unroll
  for (int r = 0; r < 4; ++r) {
    float mx = s[r][0];
#pragma unroll
    for (int j = 1; j < 8; ++j) mx = fmaxf(mx, s[r][j]);
    float sum = 0.f;
#pragma unroll
    for (int j = 0; j < 8; ++j) {
      float e = __expf(0.125f * (s[r][j] - mx));  // SCALE = 1/sqrt(64)
      p[r][j] = e;
      sum += e;
    }
    float inv = 1.f / sum;
#pragma unroll
    for (int j = 0; j < 8; ++j) p[r][j] *= inv;
  }

  float o[4][16];
#pragma unroll
  for (int r = 0; r < 4; ++r)
#pragma unroll
    for (int c = 0; c < 16; ++c) o[r][c] = 0.f;

#pragma unroll
  for (int j = 0; j < 8; ++j) {
    const unsigned short* vp = V + gbase + (size_t)j * 1024 + coff;
    u16x8 a = *reinterpret_cast<const u16x8*>(vp);
    u16x8 b = *reinterpret_cast<const u16x8*>(vp + 8);
    float vv[16];
#pragma unroll
    for (int c = 0; c < 8; ++c) { vv[c] = bf2f(a[c]); vv[8 + c] = bf2f(b[c]); }
#pragma unroll
    for (int r = 0; r < 4; ++r)
#pragma unroll
      for (int c = 0; c < 16; ++c) o[r][c] += p[r][j] * vv[c];
  }

#pragma unroll
  for (int r = 0; r < 4; ++r) {
    float* op = out + gbase + (size_t)(rh * 4 + r) * 1024 + coff;
    f32x4 v0 = {o[r][0], o[r][1], o[r][2], o[r][3]};
    f32x4 v1 = {o[r][4], o[r][5], o[r][6], o[r][7]};
    f32x4 v2 = {o[r][8], o[r][9], o[r][10], o[r][11]};
    f32x4 v3 = {o[r][12], o[r][13], o[r][14], o[r][15]};
    reinterpret_cast<f32x4*>(op)[0] = v0;
    reinterpret_cast<f32x4*>(op)[1] = v1;
    reinterpret_cast<f32x4*>(op)[2] = v2;
    reinterpret_cast<f32x4*>(op)[3] = v3;
  }
}

// ------------------------------------------------------------------- launch
extern "C" void kernel_launch(void* const* d_in, const int* in_sizes, int n_in,
                              void* d_out, int out_size, void* d_ws, size_t ws_size,
                              hipStream_t stream) {
  const float* Xq = (const float*)d_in[0];
  const float* Xk = (const float*)d_in[1];
  const float* Xv = (const float*)d_in[2];
  const float* Wq = (const float*)d_in[3];
  const float* bq = (const float*)d_in[4];
  const float* Wk = (const float*)d_in[5];
  const float* bk = (const float*)d_in[6];
  const float* Wv = (const float*)d_in[7];
  const float* bv = (const float*)d_in[8];

  unsigned short* ws = (unsigned short*)d_ws;
  unsigned short* Wb = ws;                              // 3 x 1M bf16 (6 MB), linear
  unsigned short* QKV = ws + (size_t)3 * 1024 * 1024;   // 3 x 8M bf16 (48 MB)

  cvt_w<<<1536, 256, 0, stream>>>(Wq, Wk, Wv, Wb);
  gemm3<<<1536, 256, 0, stream>>>(Xq, Xk, Xv, Wb, bq, bk, bv, QKV);
  attn_kernel<<<512, 256, 0, stream>>>(QKV, (float*)d_out);
}

// Round 4
// 98.850 us; speedup vs baseline: 2.2798x; 2.2798x over previous
//
#include <hip/hip_runtime.h>

// MultiHeadAttention_137438953529 on gfx950.
// B=8, S=1024, E=1024, H=16, D=64.  The reference's reshapes are flat
// reinterpretations => attention mixes only groups of 8 consecutive rows of
// the (8192 x 1024) projected matrices, per 64-wide head slice.
//
// R4: m97-faithful pipelined GEMM.  The R1/R3 flaw was staging tile kt at the
// top of iter kt and consuming it the same iter behind a vmcnt(0) sync ->
// every iter ate a full global latency (MfmaUtil 9-14%).  Now:
//  - dbuf A+B LDS (32 KiB): iter kt stages tile kt+1 (B via global_load_lds
//    with source-side swizzle; A via 2-iter-ahead f32 reg prefetch + cvt_pk +
//    swizzled ds_write), computes tile kt.
//  - end-of-iter fence: lgkmcnt(0) + vmcnt(4) (glds pinned oldest via
//    sched_barrier) -> glds drained, A prefetch stays in flight.
//  - XCD-family block decode (kept from R3: FETCH 88 MB, X read ~once).
//  - (row>>1)&3 chunk XOR on both LDS tiles (kept: 0 bank conflicts).
//  - 32 KiB LDS + launch_bounds(256,3) -> ~3 blocks/CU TLP.

typedef __attribute__((ext_vector_type(4))) float f32x4;
typedef __attribute__((ext_vector_type(8))) short bf16x8;   // MFMA A/B fragment
typedef __attribute__((ext_vector_type(8))) unsigned short u16x8;

#define WAIT_LGKM0 asm volatile("s_waitcnt lgkmcnt(0)" ::: "memory")
#define WAIT_VM(n) asm volatile("s_waitcnt vmcnt(" #n ")" ::: "memory")

__device__ __forceinline__ unsigned short f2bf(float f) {
  unsigned int u = __builtin_bit_cast(unsigned int, f);
  u += 0x7fffu + ((u >> 16) & 1u);          // round-to-nearest-even
  return (unsigned short)(u >> 16);
}
__device__ __forceinline__ float bf2f(unsigned short b) {
  return __builtin_bit_cast(float, ((unsigned int)b) << 16);
}
__device__ __forceinline__ u16x8 pack8(f32x4 a, f32x4 b) {
  u16x8 o;
  o[0] = f2bf(a[0]); o[1] = f2bf(a[1]); o[2] = f2bf(a[2]); o[3] = f2bf(a[3]);
  o[4] = f2bf(b[0]); o[5] = f2bf(b[1]); o[6] = f2bf(b[2]); o[7] = f2bf(b[3]);
  return o;
}
// 8x f32 -> 8x bf16 via packed cvt (RNE)
__device__ __forceinline__ u16x8 cvt8(f32x4 a, f32x4 b) {
  union { unsigned int u[4]; u16x8 v; } r;
  asm("v_cvt_pk_bf16_f32 %0, %1, %2" : "=v"(r.u[0]) : "v"(a[0]), "v"(a[1]));
  asm("v_cvt_pk_bf16_f32 %0, %1, %2" : "=v"(r.u[1]) : "v"(a[2]), "v"(a[3]));
  asm("v_cvt_pk_bf16_f32 %0, %1, %2" : "=v"(r.u[2]) : "v"(b[0]), "v"(b[1]));
  asm("v_cvt_pk_bf16_f32 %0, %1, %2" : "=v"(r.u[3]) : "v"(b[2]), "v"(b[3]));
  return r.v;
}

__device__ __forceinline__ void gload_lds16(const unsigned short* g, unsigned short* l) {
  __builtin_amdgcn_global_load_lds(
      (const __attribute__((address_space(1))) unsigned int*)g,
      (__attribute__((address_space(3))) unsigned int*)l, 16, 0, 0);
}

// --------------------------------------------------- W -> bf16 (linear layout)
__global__ __launch_bounds__(256) void cvt_w(const float* __restrict__ Wq,
                                             const float* __restrict__ Wk,
                                             const float* __restrict__ Wv,
                                             unsigned short* __restrict__ Wb) {
  int i = blockIdx.x * 256 + threadIdx.x;     // 0 .. 393216 (3 * 131072 chunks of 8)
  int proj = i >> 17;
  int local = i & 131071;
  const float* src = (proj == 0 ? Wq : proj == 1 ? Wk : Wv) + (size_t)local * 8;
  f32x4 a = reinterpret_cast<const f32x4*>(src)[0];
  f32x4 b = reinterpret_cast<const f32x4*>(src)[1];
  *reinterpret_cast<u16x8*>(Wb + (size_t)proj * 1048576 + (size_t)local * 8) = pack8(a, b);
}

// ------------------------------------------------------------ QKV projection
// C[8192x1024] = X @ W^T + bias per proj.  BM=BN=128, BK=32, 256 threads,
// 4 waves (2x2), per-wave 64x64 (4x4 frags of 16x16x32 bf16 MFMA), 32 K-iters.

__device__ __forceinline__ void issueA(const float* __restrict__ X, int rowBase,
                                       int kt2, int t, f32x4 r[4]) {
  const int ra = t >> 2;                      // row 0..63 (and +64)
  const int sc = t & 3;                       // 8-elem k-slot
  const float* p0 = X + (size_t)(rowBase + ra) * 1024 + kt2 * 32 + sc * 8;
  const float* p1 = p0 + (size_t)64 * 1024;
  r[0] = *reinterpret_cast<const f32x4*>(p0);
  r[1] = *reinterpret_cast<const f32x4*>(p0 + 4);
  r[2] = *reinterpret_cast<const f32x4*>(p1);
  r[3] = *reinterpret_cast<const f32x4*>(p1 + 4);
}

__device__ __forceinline__ void writeA(unsigned short* As, int t, const f32x4 r[4]) {
  const int ra = t >> 2;
  const int sc = t & 3;
  const int r0 = ra, r1 = ra + 64;
  *reinterpret_cast<u16x8*>(As + r0 * 32 + ((sc ^ ((r0 >> 1) & 3)) * 8)) = cvt8(r[0], r[1]);
  *reinterpret_cast<u16x8*>(As + r1 * 32 + ((sc ^ ((r1 >> 1) & 3)) * 8)) = cvt8(r[2], r[3]);
}

__global__ __launch_bounds__(256, 3) void gemm4(
    const float* __restrict__ Xq, const float* __restrict__ Xk, const float* __restrict__ Xv,
    const unsigned short* __restrict__ Wb,
    const float* __restrict__ bq, const float* __restrict__ bk, const float* __restrict__ bv,
    unsigned short* __restrict__ QKV) {
  // XCD-family decode: XCD c (dispatch round-robin d%8) owns x in [8c,8c+8);
  // consecutive-in-time blocks on one XCD share x (X panel L2-resident, read
  // ~once from HBM) and sweep y (W panels cycle; L2+L3 absorb).
  const int d = blockIdx.x;
  const int xcd = d & 7;
  const int k5 = d >> 3;
  const int y = k5 & 7;
  const int rest = k5 >> 3;       // 0..23
  const int proj = rest >> 3;     // 0..2
  const int xg = rest & 7;
  const int x = xcd * 8 + xg;     // 0..63

  const float* X = (proj == 0) ? Xq : (proj == 1) ? Xk : Xv;
  const float* bias = (proj == 0) ? bq : (proj == 1) ? bk : bv;
  const unsigned short* W = Wb + (size_t)proj * 1048576;
  unsigned short* O = QKV + (size_t)proj * 8388608;

  const int rowBase = x * 128;
  const int colBase = y * 128;

  __shared__ alignas(16) unsigned short As[2][4096];   // [128 rows][32 k], chunk-XOR'd
  __shared__ alignas(16) unsigned short Bs[2][4096];

  const int t = threadIdx.x;
  const int l = t & 63;
  const int w = t >> 6;
  const int wr = w >> 1, wc = w & 1;

  f32x4 acc[4][4];
#pragma unroll
  for (int m = 0; m < 4; ++m)
#pragma unroll
    for (int n = 0; n < 4; ++n) acc[m][n] = f32x4{0.f, 0.f, 0.f, 0.f};

  // fragment read offsets (ushort units), swizzle-matched: logical chunk g of
  // row r lives at physical chunk g ^ ((r>>1)&3)
  int aoff[4], boff[4];
#pragma unroll
  for (int m = 0; m < 4; ++m) {
    const int row = wr * 64 + m * 16 + (l & 15);
    aoff[m] = row * 32 + (((l >> 4) ^ ((row >> 1) & 3)) * 8);
  }
#pragma unroll
  for (int n = 0; n < 4; ++n) {
    const int row = wc * 64 + n * 16 + (l & 15);
    boff[n] = row * 32 + (((l >> 4) ^ ((row >> 1) & 3)) * 8);
  }

  // B staging: thread t, call j: linear dest byte o = (j*4+w)*1024 + l*16;
  // row = o>>6, phys chunk = l&3; source chunk = (l&3) ^ ((row>>1)&3)
  const int srow0 = w * 16 + (l >> 2);
  const int sc = l & 3;
#define STAGE_B(buf, kt)                                                          \
  {                                                                               \
    _Pragma("unroll") for (int j = 0; j < 2; ++j) {                               \
      const int row = j * 64 + srow0;                                             \
      const int cp = sc ^ ((row >> 1) & 3);                                       \
      gload_lds16(W + (size_t)(colBase + row) * 1024 + (kt) * 32 + cp * 8,        \
                  &Bs[buf][0] + (j * 4 + w) * 512 + l * 8);                       \
    }                                                                             \
  }

#define COMPUTE(buf)                                                              \
  {                                                                               \
    bf16x8 af[4], bfr[4];                                                         \
    _Pragma("unroll") for (int m = 0; m < 4; ++m)                                 \
        af[m] = *reinterpret_cast<const bf16x8*>(&As[buf][0] + aoff[m]);          \
    _Pragma("unroll") for (int n = 0; n < 4; ++n)                                 \
        bfr[n] = *reinterpret_cast<const bf16x8*>(&Bs[buf][0] + boff[n]);         \
    __builtin_amdgcn_s_setprio(1);                                                \
    _Pragma("unroll") for (int m = 0; m < 4; ++m)                                 \
        _Pragma("unroll") for (int n = 0; n < 4; ++n)                             \
            acc[m][n] =                                                           \
                __builtin_amdgcn_mfma_f32_16x16x32_bf16(af[m], bfr[n], acc[m][n], \
                                                        0, 0, 0);                 \
    __builtin_amdgcn_s_setprio(0);                                                \
  }

  f32x4 aRa[4], aRb[4];

  // ---- prologue: buf0 <- tile 0 (A+B), aRa <- tile 1 A-data
  issueA(X, rowBase, 0, t, aRa);
  STAGE_B(0, 0);
  __builtin_amdgcn_sched_barrier(0);
  writeA(&As[0][0], t, aRa);          // compiler waits aRa's 4 loads (oldest)
  issueA(X, rowBase, 1, t, aRa);
  WAIT_LGKM0;
  WAIT_VM(4);                         // drains glds(0); aRa(1) stays in flight
  __builtin_amdgcn_sched_barrier(0);
  __builtin_amdgcn_s_barrier();
  __builtin_amdgcn_sched_barrier(0);

  // ---- main loop, manual 2-step unroll (static buffers + reg ping-pong)
  for (int kt = 0; kt < 32; kt += 2) {
    // even: compute buf0 (tile kt); stage kt+1 -> buf1; aRa holds kt+1
    {
      STAGE_B(1, kt + 1);                       // 2 glds, oldest this iter
      __builtin_amdgcn_sched_barrier(0);
      if (kt + 2 < 32) issueA(X, rowBase, kt + 2, t, aRb);
      writeA(&As[1][0], t, aRa);
      COMPUTE(0);
      WAIT_LGKM0;
      if (kt + 2 < 32) { WAIT_VM(4); } else { WAIT_VM(0); }
      __builtin_amdgcn_sched_barrier(0);
      __builtin_amdgcn_s_barrier();
      __builtin_amdgcn_sched_barrier(0);
    }
    // odd: compute buf1 (tile kt+1); stage kt+2 -> buf0; aRb holds kt+2
    {
      if (kt + 2 < 32) {
        STAGE_B(0, kt + 2);
        __builtin_amdgcn_sched_barrier(0);
        if (kt + 3 < 32) issueA(X, rowBase, kt + 3, t, aRa);
        writeA(&As[0][0], t, aRb);
      }
      COMPUTE(1);
      if (kt + 2 < 32) {
        WAIT_LGKM0;
        if (kt + 3 < 32) { WAIT_VM(4); } else { WAIT_VM(0); }
        __builtin_amdgcn_sched_barrier(0);
        __builtin_amdgcn_s_barrier();
        __builtin_amdgcn_sched_barrier(0);
      }
    }
  }

  // ---- epilogue: C/D layout col=lane&15, row=(lane>>4)*4+reg
#pragma unroll
  for (int n = 0; n < 4; ++n) {
    const int col = colBase + wc * 64 + n * 16 + (l & 15);
    const float bn = bias[col];
#pragma unroll
    for (int m = 0; m < 4; ++m) {
      const int row0 = rowBase + wr * 64 + m * 16 + (l >> 4) * 4;
#pragma unroll
      for (int j = 0; j < 4; ++j)
        O[(size_t)(row0 + j) * 1024 + col] = f2bf(acc[m][n][j] + bn);
    }
  }
#undef STAGE_B
#undef COMPUTE
}

// ------------------------------------------------------------------ attention
// thread = (n group, head h, d-quarter dq, row-half rh): 4 q-rows x 16 d-cols
// of the 8-key attention; QK partial dots reduced across 4 dq lanes.
__global__ __launch_bounds__(256) void attn_kernel(const unsigned short* __restrict__ QKV,
                                                   float* __restrict__ out) {
  const int t = threadIdx.x;
  const int lane = t & 63;
  const int dq = lane & 3;
  const int h = (lane >> 2) & 15;
  const int rh = (t >> 6) & 1;
  const int n = blockIdx.x * 2 + (t >> 7);

  const unsigned short* Q = QKV;
  const unsigned short* K = QKV + (size_t)8388608;
  const unsigned short* V = QKV + (size_t)16777216;
  const size_t gbase = (size_t)n * 8192;
  const int coff = h * 64 + dq * 16;

  float q[4][16];
#pragma unroll
  for (int r = 0; r < 4; ++r) {
    const unsigned short* qp = Q + gbase + (size_t)(rh * 4 + r) * 1024 + coff;
    u16x8 a = *reinterpret_cast<const u16x8*>(qp);
    u16x8 b = *reinterpret_cast<const u16x8*>(qp + 8);
#pragma unroll
    for (int c = 0; c < 8; ++c) { q[r][c] = bf2f(a[c]); q[r][8 + c] = bf2f(b[c]); }
  }

  float s[4][8];
#pragma unroll
  for (int r = 0; r < 4; ++r)
#pragma unroll
    for (int j = 0; j < 8; ++j) s[r][j] = 0.f;

#pragma unroll
  for (int j = 0; j < 8; ++j) {
    const unsigned short* kp = K + gbase + (size_t)j * 1024 + coff;
    u16x8 a = *reinterpret_cast<const u16x8*>(kp);
    u16x8 b = *reinterpret_cast<const u16x8*>(kp + 8);
    float kv[16];
#pragma unroll
    for (int c = 0; c < 8; ++c) { kv[c] = bf2f(a[c]); kv[8 + c] = bf2f(b[c]); }
#pragma unroll
    for (int r = 0; r < 4; ++r) {
      float acc = 0.f;
#pragma unroll
      for (int c = 0; c < 16; ++c) acc += q[r][c] * kv[c];
      s[r][j] += acc;
    }
  }

#pragma unroll
  for (int r = 0; r < 4; ++r)
#pragma unroll
    for (int j = 0; j < 8; ++j) {
      float v = s[r][j];
      v += __shfl_xor(v, 1, 64);
      v += __shfl_xor(v, 2, 64);
      s[r][j] = v;
    }

  float p[4][8];
#pragma unroll
  for (int r = 0; r < 4; ++r) {
    float mx = s[r][0];
#pragma unroll
    for (int j = 1; j < 8; ++j) mx = fmaxf(mx, s[r][j]);
    float sum = 0.f;
#pragma unroll
    for (int j = 0; j < 8; ++j) {
      float e = __expf(0.125f * (s[r][j] - mx));  // SCALE = 1/sqrt(64)
      p[r][j] = e;
      sum += e;
    }
    float inv = 1.f / sum;
#pragma unroll
    for (int j = 0; j < 8; ++j) p[r][j] *= inv;
  }

  float o[4][16];
#pragma unroll
  for (int r = 0; r < 4; ++r)
#pragma unroll
    for (int c = 0; c < 16; ++c) o[r][c] = 0.f;

#pragma unroll
  for (int j = 0; j < 8; ++j) {
    const unsigned short* vp = V + gbase + (size_t)j * 1024 + coff;
    u16x8 a = *reinterpret_cast<const u16x8*>(vp);
    u16x8 b = *reinterpret_cast<const u16x8*>(vp + 8);
    float vv[16];
#pragma unroll
    for (int c = 0; c < 8; ++c) { vv[c] = bf2f(a[c]); vv[8 + c] = bf2f(b[c]); }
#pragma unroll
    for (int r = 0; r < 4; ++r)
#pragma unroll
      for (int c = 0; c < 16; ++c) o[r][c] += p[r][j] * vv[c];
  }

#pragma unroll
  for (int r = 0; r < 4; ++r) {
    float* op = out + gbase + (size_t)(rh * 4 + r) * 1024 + coff;
    f32x4 v0 = {o[r][0], o[r][1], o[r][2], o[r][3]};
    f32x4 v1 = {o[r][4], o[r][5], o[r][6], o[r][7]};
    f32x4 v2 = {o[r][8], o[r][9], o[r][10], o[r][11]};
    f32x4 v3 = {o[r][12], o[r][13], o[r][14], o[r][15]};
    reinterpret_cast<f32x4*>(op)[0] = v0;
    reinterpret_cast<f32x4*>(op)[1] = v1;
    reinterpret_cast<f32x4*>(op)[2] = v2;
    reinterpret_cast<f32x4*>(op)[3] = v3;
  }
}

// ------------------------------------------------------------------- launch
extern "C" void kernel_launch(void* const* d_in, const int* in_sizes, int n_in,
                              void* d_out, int out_size, void* d_ws, size_t ws_size,
                              hipStream_t stream) {
  const float* Xq = (const float*)d_in[0];
  const float* Xk = (const float*)d_in[1];
  const float* Xv = (const float*)d_in[2];
  const float* Wq = (const float*)d_in[3];
  const float* bq = (const float*)d_in[4];
  const float* Wk = (const float*)d_in[5];
  const float* bk = (const float*)d_in[6];
  const float* Wv = (const float*)d_in[7];
  const float* bv = (const float*)d_in[8];

  unsigned short* ws = (unsigned short*)d_ws;
  unsigned short* Wb = ws;                              // 3 x 1M bf16 (6 MB), linear
  unsigned short* QKV = ws + (size_t)3 * 1024 * 1024;   // 3 x 8M bf16 (48 MB)

  cvt_w<<<1536, 256, 0, stream>>>(Wq, Wk, Wv, Wb);
  gemm4<<<1536, 256, 0, stream>>>(Xq, Xk, Xv, Wb, bq, bk, bv, QKV);
  attn_kernel<<<512, 256, 0, stream>>>(QKV, (float*)d_out);
}